// Round 1
// baseline (149.801 us; speedup 1.0000x reference)
//
#include <hip/hip_runtime.h>
#include <math.h>

#define B_ 2
#define T_ 16
#define N_ 128
#define CI 64     // INP = COND = 64
#define CO 128    // OUT

// ---------- small float4 helpers (avoid relying on vector operators) ----------
__device__ __forceinline__ float4 f4add(float4 a, float4 b) {
  return make_float4(a.x + b.x, a.y + b.y, a.z + b.z, a.w + b.w);
}
__device__ __forceinline__ float4 f4max(float4 a, float4 b) {
  return make_float4(fmaxf(a.x, b.x), fmaxf(a.y, b.y), fmaxf(a.z, b.z), fmaxf(a.w, b.w));
}
__device__ __forceinline__ void f4fma(float4& acc, float s, float4 v) {
  acc.x = fmaf(s, v.x, acc.x);
  acc.y = fmaf(s, v.y, acc.y);
  acc.z = fmaf(s, v.z, acc.z);
  acc.w = fmaf(s, v.w, acc.w);
}

// =====================================================================
// Kernel 1: A[b,t,n,o] = x[b,t,n,:] @ Weff1(cat) + bias
//           Bp[b,t,n,o] = x[b,t,n,:] @ Weff2(cat)
// where Weff1 = f0*W[0:64] + W[64:128] + f2*W[128:192] (per-t masks),
//       Weff2 = f0*W[192:256] + W[256:320] + f2*W[320:384]
// grid: B*T*8 blocks (16 rows each), 128 threads, thread tile 2n x 8o.
// =====================================================================
__global__ __launch_bounds__(128) void k_ab(
    const float* __restrict__ x, const float* __restrict__ W,
    const float* __restrict__ bias, float* __restrict__ A, float* __restrict__ Bp)
{
  __shared__ float xL[16][CI + 1];                 // +1 pad: breaks 4-way bank alias on broadcast reads
  __shared__ __align__(16) float W1L[CI][CO];      // Weff1[c][o]
  __shared__ __align__(16) float W2L[CI][CO];      // Weff2[c][o]

  int blk = blockIdx.x;
  int nt = blk & 7;
  int t  = (blk >> 3) & 15;
  int b  = blk >> 7;
  int n0 = nt * 16;
  float f0 = (t != 0)      ? 1.0f : 0.0f;
  float f2 = (t != T_ - 1) ? 1.0f : 0.0f;
  int tid = threadIdx.x;

  // stage x rows (16 x 64)
  for (int idx = tid; idx < 16 * CI; idx += 128) {
    int r = idx >> 6, c = idx & 63;
    xL[r][c] = x[(((long)(b * T_ + t) * N_) + n0 + r) * CI + c];
  }
  // build Weff in LDS (W is 256 KB, L2-resident; coalesced over o)
  float* w1f = &W1L[0][0];
  float* w2f = &W2L[0][0];
  for (int idx = tid; idx < CI * CO; idx += 128) {
    w1f[idx] = f0 * W[idx]         + W[8192 + idx]  + f2 * W[16384 + idx];
    w2f[idx] = f0 * W[24576 + idx] + W[32768 + idx] + f2 * W[40960 + idx];
  }
  __syncthreads();

  int og  = tid & 15;       // o-group: owns quads [og*4..og*4+3] and [64+og*4 ..]
  int ng  = tid >> 4;       // 0..7 -> rows 2*ng, 2*ng+1
  int og4 = og * 4;
  int r0  = ng * 2;

  float4 bqa = *(const float4*)&bias[og4];
  float4 bqb = *(const float4*)&bias[og4 + 64];
  float4 a1a = bqa, a1b = bqb, a1c = bqa, a1d = bqb;   // A: row0 (a,b), row1 (c,d)
  float4 a2a = make_float4(0,0,0,0), a2b = a2a, a2c = a2a, a2d = a2a;  // Bp

  #pragma unroll 4
  for (int c = 0; c < CI; c++) {
    float x0 = xL[r0][c];
    float x1 = xL[r0 + 1][c];
    float4 wA = *(const float4*)&W1L[c][og4];
    float4 wB = *(const float4*)&W1L[c][og4 + 64];
    float4 vA = *(const float4*)&W2L[c][og4];
    float4 vB = *(const float4*)&W2L[c][og4 + 64];
    f4fma(a1a, x0, wA); f4fma(a1b, x0, wB);
    f4fma(a1c, x1, wA); f4fma(a1d, x1, wB);
    f4fma(a2a, x0, vA); f4fma(a2b, x0, vB);
    f4fma(a2c, x1, vA); f4fma(a2d, x1, vB);
  }

  long rb0 = ((long)(b * T_ + t) * N_ + n0 + r0) * CO;
  long rb1 = rb0 + CO;
  *(float4*)&A[rb0 + og4]       = a1a;
  *(float4*)&A[rb0 + og4 + 64]  = a1b;
  *(float4*)&A[rb1 + og4]       = a1c;
  *(float4*)&A[rb1 + og4 + 64]  = a1d;
  *(float4*)&Bp[rb0 + og4]      = a2a;
  *(float4*)&Bp[rb0 + og4 + 64] = a2b;
  *(float4*)&Bp[rb1 + og4]      = a2c;
  *(float4*)&Bp[rb1 + og4 + 64] = a2d;
}

// =====================================================================
// Kernel 2: one block per (b,i).
// Phase A: Cp[j][o] = cond[b,i,j,:]@Wc1 + cond[b,j,i,:]@Wc2 into LDS.
//   Register-tiled f32 GEMM: 256 threads = 16(jg) x 16(og), each owns
//   8j x 8o (j = jg+16k, o = og+16m). Operands in LDS rows padded to 68
//   floats (16B-aligned, bank-quad spread; worst aliasing 2-way = free).
// Phase B: out[b,t,i,o] = silu( max_j(Bp[t,j,o] + Cp[j,o]) + A[t,i,o] )
//   fast path (max >= 0, silu monotone there); exact slow path otherwise.
// =====================================================================
__device__ __forceinline__ void gemm_step(float acc[8][8], const float* Wt,
                                          const float* Cd, int jg, int og) {
  for (int c = 0; c < 64; c += 4) {
    float4 wv[8], cv[8];
    #pragma unroll
    for (int m = 0; m < 8; m++) wv[m] = *(const float4*)&Wt[(og + 16 * m) * 68 + c];
    #pragma unroll
    for (int k = 0; k < 8; k++) cv[k] = *(const float4*)&Cd[(jg + 16 * k) * 68 + c];
    #pragma unroll
    for (int k = 0; k < 8; k++) {
      #pragma unroll
      for (int m = 0; m < 8; m++) {
        acc[k][m] = fmaf(cv[k].x, wv[m].x, acc[k][m]);
        acc[k][m] = fmaf(cv[k].y, wv[m].y, acc[k][m]);
        acc[k][m] = fmaf(cv[k].z, wv[m].z, acc[k][m]);
        acc[k][m] = fmaf(cv[k].w, wv[m].w, acc[k][m]);
      }
    }
  }
}

__device__ float slow_silu_max(const float* __restrict__ BpT,
                               const float* __restrict__ CpS, float a, int o) {
  // exact path for the rare case max_j s_j < 0 (all-negative row)
  float m = -3.4e38f;
  for (int j = 0; j < 128; j++) {
    float v = a + BpT[j * CO + o] + CpS[j * 128 + o];
    float sil = v / (1.0f + __expf(-v));
    m = fmaxf(m, sil);
  }
  return m;
}

__device__ __forceinline__ float fast_silu(float s) {
  // s >= 0 here: exp(-s) in (0,1], no overflow
  return s / (1.0f + __expf(-s));
}

__global__ __launch_bounds__(256) void k_main(
    const float* __restrict__ cond, const float* __restrict__ W,
    const float* __restrict__ A, const float* __restrict__ Bp,
    float* __restrict__ out)
{
  // union: phase A uses Wt[128][68] + Cd[128][68] (69632 B); phase B overlays Cp[128][128]
  __shared__ __align__(16) float smem[2 * 128 * 68];
  float* Wt = smem;              // Wt[o*68 + c] = Wc[c][o]
  float* Cd = smem + 128 * 68;   // Cd[j*68 + c]
  float* Cp = smem;              // Cp[j*128 + o] overlay

  int blk = blockIdx.x;
  int i = blk & 127;
  int b = blk >> 7;
  int tid = threadIdx.x;
  int jg = tid >> 4;     // 0..15
  int og = tid & 15;     // 0..15

  float acc[8][8];
  #pragma unroll
  for (int k = 0; k < 8; k++)
    #pragma unroll
    for (int m = 0; m < 8; m++) acc[k][m] = 0.0f;

  // ---- sub-phase 1: cond[b,i,:,:] @ Wc1 (W rows 384..448) ----
  for (int idx = tid; idx < 64 * 128; idx += 256) {
    int c = idx >> 7, o = idx & 127;
    Wt[o * 68 + c] = W[49152 + idx];          // transpose into [o][c]
  }
  for (int idx = tid; idx < 128 * 64; idx += 256) {
    int j = idx >> 6, c = idx & 63;
    Cd[j * 68 + c] = cond[((long)(b * N_ + i) * N_ + j) * CI + c];
  }
  __syncthreads();
  gemm_step(acc, Wt, Cd, jg, og);
  __syncthreads();

  // ---- sub-phase 2: cond[b,:,i,:] @ Wc2 (W rows 448..512) ----
  for (int idx = tid; idx < 64 * 128; idx += 256) {
    int c = idx >> 7, o = idx & 127;
    Wt[o * 68 + c] = W[49152 + 8192 + idx];
  }
  for (int idx = tid; idx < 128 * 64; idx += 256) {
    int j = idx >> 6, c = idx & 63;
    Cd[j * 68 + c] = cond[((long)(b * N_ + j) * N_ + i) * CI + c];
  }
  __syncthreads();
  gemm_step(acc, Wt, Cd, jg, og);
  __syncthreads();

  // ---- write Cp (overlays Wt/Cd — all reads are done) ----
  #pragma unroll
  for (int k = 0; k < 8; k++)
    #pragma unroll
    for (int m = 0; m < 8; m++)
      Cp[(jg + 16 * k) * 128 + og + 16 * m] = acc[k][m];
  __syncthreads();

  // ---- phase B: max-plus reduction over j, then one SiLU ----
  int o4 = tid & 31;    // quad id: o = o4*4..o4*4+3
  int tg = tid >> 5;    // 0..7
  const float4* Cp4 = (const float4*)Cp;

  for (int ts = 0; ts < 2; ts++) {
    int t = tg + 8 * ts;
    const float* BpT = Bp + (long)(b * T_ + t) * N_ * CO;
    const float4* Bp4 = (const float4*)BpT;
    float4 m0 = make_float4(-3.4e38f, -3.4e38f, -3.4e38f, -3.4e38f);
    float4 m1 = m0;
    #pragma unroll 2
    for (int j = 0; j < 128; j += 2) {
      float4 bp0 = Bp4[j * 32 + o4];
      float4 cp0 = Cp4[j * 32 + o4];
      float4 bp1 = Bp4[(j + 1) * 32 + o4];
      float4 cp1 = Cp4[(j + 1) * 32 + o4];
      m0 = f4max(m0, f4add(bp0, cp0));
      m1 = f4max(m1, f4add(bp1, cp1));
    }
    float4 mx = f4max(m0, m1);
    long abase = ((long)(b * T_ + t) * N_ + i) * CO + o4 * 4;
    float4 av = *(const float4*)&A[abase];
    float4 s = f4add(mx, av);
    float4 r;
    r.x = (s.x >= 0.0f) ? fast_silu(s.x) : slow_silu_max(BpT, Cp, av.x, o4 * 4 + 0);
    r.y = (s.y >= 0.0f) ? fast_silu(s.y) : slow_silu_max(BpT, Cp, av.y, o4 * 4 + 1);
    r.z = (s.z >= 0.0f) ? fast_silu(s.z) : slow_silu_max(BpT, Cp, av.z, o4 * 4 + 2);
    r.w = (s.w >= 0.0f) ? fast_silu(s.w) : slow_silu_max(BpT, Cp, av.w, o4 * 4 + 3);
    *(float4*)&out[abase] = r;
  }
}

extern "C" void kernel_launch(void* const* d_in, const int* in_sizes, int n_in,
                              void* d_out, int out_size, void* d_ws, size_t ws_size,
                              hipStream_t stream) {
  const float* x    = (const float*)d_in[0];   // (2,16,128,64)
  const float* cond = (const float*)d_in[1];   // (2,128,128,64)
  const float* W    = (const float*)d_in[2];   // (512,128)
  const float* bias = (const float*)d_in[3];   // (128,)
  float* out = (float*)d_out;                  // (2,16,128,128)

  float* A  = (float*)d_ws;                          // 524288 floats (bias folded in)
  float* Bp = A + (size_t)B_ * T_ * N_ * CO;         // 524288 floats

  k_ab<<<B_ * T_ * 8, 128, 0, stream>>>(x, W, bias, A, Bp);
  k_main<<<B_ * N_, 256, 0, stream>>>(cond, W, A, Bp, out);
}

// Round 2
// 148.829 us; speedup vs baseline: 1.0065x; 1.0065x over previous
//
#include <hip/hip_runtime.h>
#include <math.h>

#define B_ 2
#define T_ 16
#define N_ 128
#define CI 64     // INP = COND = 64
#define CO 128    // OUT

// ws layout (floats):
//   A   [0,           524288)   : a + bias, [b,t,n,o]
//   Bp  [524288,      1048576)  : bpart,    [b,t,n,o]
//   WT  [1048576,     1097728)  : 3 x [c][256] effective weights (cls: 0=t0,1=mid,2=tlast)
//   Cp  [1097728,     5292032)  : cpart,    [b,i,j,o]   (16.8 MB)
#define A_OFF   0
#define BP_OFF  524288
#define WT_OFF  1048576
#define CP_OFF  1097728

__device__ __forceinline__ float4 f4add(float4 a, float4 b) {
  return make_float4(a.x + b.x, a.y + b.y, a.z + b.z, a.w + b.w);
}
__device__ __forceinline__ float4 f4max(float4 a, float4 b) {
  return make_float4(fmaxf(a.x, b.x), fmaxf(a.y, b.y), fmaxf(a.z, b.z), fmaxf(a.w, b.w));
}
__device__ __forceinline__ void f4fma(float4& acc, float s, float4 v) {
  acc.x = fmaf(s, v.x, acc.x);
  acc.y = fmaf(s, v.y, acc.y);
  acc.z = fmaf(s, v.z, acc.z);
  acc.w = fmaf(s, v.w, acc.w);
}

// =====================================================================
// k_prep: WT[cls][c][oo], oo in [0,256): 0:128 = Weff1 col, 128:256 = Weff2 col
// Weff1 = f0*W[0:64] + W[64:128] + f2*W[128:192];  Weff2 same on rows 192..384
// grid 48 x 256, one float4 per thread (48*256*4 = 49152 floats exactly)
// =====================================================================
__global__ __launch_bounds__(256) void k_prep(const float* __restrict__ W,
                                              float* __restrict__ WT) {
  int e4 = blockIdx.x * 256 + threadIdx.x;      // float4 index
  int flat = e4 * 4;
  int cls = flat / 16384;
  int rem = flat - cls * 16384;
  int c = rem >> 8;
  int oo = rem & 255;
  float f0 = (cls == 0) ? 0.0f : 1.0f;
  float f2 = (cls == 2) ? 0.0f : 1.0f;
  const float4* W4 = (const float4*)W;
  int o = oo & 127;
  int base = (oo < 128) ? 0 : 24576;            // Weff1 rows 0..192, Weff2 rows 192..384
  int wi = (base + c * 128 + o) >> 2;
  float4 wa = W4[wi];
  float4 wb = W4[wi + 2048];                    // +8192 floats
  float4 wc = W4[wi + 4096];                    // +16384 floats
  float4 r = make_float4(f0 * wa.x + wb.x + f2 * wc.x,
                         f0 * wa.y + wb.y + f2 * wc.y,
                         f0 * wa.z + wb.z + f2 * wc.z,
                         f0 * wa.w + wb.w + f2 * wc.w);
  ((float4*)WT)[e4] = r;
}

// =====================================================================
// k_ab: A[b,t,n,o] = x[b,t,n,:]@Weff1 + bias ; Bp = x@Weff2
// grid 512 = b(2) x t(16) x ntile(16, 8 rows each), 128 threads.
// thread = 2 rows x 8 cols (quad oo=q*4 in Weff1-half + quad 128+q*4 in Weff2-half)
// LDS 66 KB -> 2 blocks/CU.
// =====================================================================
__global__ __launch_bounds__(128) void k_ab(
    const float* __restrict__ x, const float* __restrict__ WT,
    const float* __restrict__ bias, float* __restrict__ A, float* __restrict__ Bp)
{
  __shared__ __align__(16) float WL[64 * 256];   // [c][oo]
  __shared__ __align__(16) float xL[8 * 68];     // [r][c], row stride 68 (16B-aligned)

  int blk = blockIdx.x;
  int nt = blk & 15;
  int t  = (blk >> 4) & 15;
  int b  = blk >> 8;
  int n0 = nt * 8;
  int cls = (t == 0) ? 0 : ((t == T_ - 1) ? 2 : 1);
  int tid = threadIdx.x;

  // stage effective weights (4096 float4)
  const float4* WT4 = (const float4*)WT + cls * 4096;
  float4* WL4 = (float4*)WL;
  #pragma unroll
  for (int k = 0; k < 32; k++) WL4[tid + k * 128] = WT4[tid + k * 128];
  // stage 8 x-rows (128 float4)
  if (tid < 128) {
    int r = tid >> 4, c4 = tid & 15;
    ((float4*)(xL + r * 68))[c4] =
        ((const float4*)x)[((long)(b * T_ + t) * N_ + n0 + r) * 16 + c4];
  }
  __syncthreads();

  int rg = tid >> 5;          // 0..3 -> rows 2rg, 2rg+1
  int q  = tid & 31;          // o-quad
  int r0 = rg * 2;

  float4 bq = *(const float4*)&bias[q * 4];
  float4 a10 = bq, a11 = bq;                    // A rows 0,1
  float4 b10 = make_float4(0, 0, 0, 0), b11 = b10;  // Bp rows 0,1

  #pragma unroll 8
  for (int c = 0; c < CI; c++) {
    float x0 = xL[r0 * 68 + c];
    float x1 = xL[(r0 + 1) * 68 + c];
    float4 w1 = WL4[c * 64 + q];
    float4 w2 = WL4[c * 64 + 32 + q];
    f4fma(a10, x0, w1); f4fma(a11, x1, w1);
    f4fma(b10, x0, w2); f4fma(b11, x1, w2);
  }

  long rb0 = ((long)(b * T_ + t) * N_ + n0 + r0) * CO + q * 4;
  *(float4*)&A[rb0]        = a10;
  *(float4*)&A[rb0 + CO]   = a11;
  *(float4*)&Bp[rb0]       = b10;
  *(float4*)&Bp[rb0 + CO]  = b11;
}

// =====================================================================
// k_cp: Cp[b,i,j,o] = cond[b,i,j,:]@Wc1 + cond[b,j,i,:]@Wc2
// grid 512 = b(2) x i(128) x jhalf(2, 64 j-rows each), 128 threads.
// thread = 8j x 8o register tile (8 jg x 16 og). LDS 52 KB -> 3 blocks/CU.
// LDS/VALU balanced: per c-quad-iter 16 b128 per 256 FMA.
// =====================================================================
__device__ __forceinline__ void gemm8x8(float acc[8][8], const float* Wt,
                                        const float* Cd, int jg, int og) {
  for (int c = 0; c < 64; c += 4) {
    float4 wv[8], cv[8];
    #pragma unroll
    for (int m = 0; m < 8; m++) wv[m] = *(const float4*)&Wt[(og + 16 * m) * 68 + c];
    #pragma unroll
    for (int k = 0; k < 8; k++) cv[k] = *(const float4*)&Cd[(jg + 8 * k) * 68 + c];
    #pragma unroll
    for (int k = 0; k < 8; k++) {
      #pragma unroll
      for (int m = 0; m < 8; m++) {
        acc[k][m] = fmaf(cv[k].x, wv[m].x, acc[k][m]);
        acc[k][m] = fmaf(cv[k].y, wv[m].y, acc[k][m]);
        acc[k][m] = fmaf(cv[k].z, wv[m].z, acc[k][m]);
        acc[k][m] = fmaf(cv[k].w, wv[m].w, acc[k][m]);
      }
    }
  }
}

__global__ __launch_bounds__(128) void k_cp(
    const float* __restrict__ cond, const float* __restrict__ W,
    float* __restrict__ Cp)
{
  __shared__ __align__(16) float Wt[128 * 68];   // [o][c] transposed weights
  __shared__ __align__(16) float Cd[64 * 68];    // [j_local][c]

  int blk = blockIdx.x;
  int jh = blk & 1;
  int i  = (blk >> 1) & 127;
  int b  = blk >> 8;
  int tid = threadIdx.x;
  int jg = tid >> 4;     // 0..7
  int og = tid & 15;     // 0..15

  float acc[8][8];
  #pragma unroll
  for (int k = 0; k < 8; k++)
    #pragma unroll
    for (int m = 0; m < 8; m++) acc[k][m] = 0.0f;

  // ---- pass 1: cond[b,i,jh*64+jl,:] @ Wc1 (W rows 384..448) ----
  for (int idx = tid; idx < 8192; idx += 128) {
    int c = idx >> 7, o = idx & 127;
    Wt[o * 68 + c] = W[49152 + idx];
  }
  for (int idx = tid; idx < 4096; idx += 128) {
    int jl = idx >> 6, c = idx & 63;
    Cd[jl * 68 + c] = cond[((long)(b * N_ + i) * N_ + jh * 64 + jl) * CI + c];
  }
  __syncthreads();
  gemm8x8(acc, Wt, Cd, jg, og);
  __syncthreads();

  // ---- pass 2: cond[b,jh*64+jl,i,:] @ Wc2 (W rows 448..512) ----
  for (int idx = tid; idx < 8192; idx += 128) {
    int c = idx >> 7, o = idx & 127;
    Wt[o * 68 + c] = W[57344 + idx];
  }
  for (int idx = tid; idx < 4096; idx += 128) {
    int jl = idx >> 6, c = idx & 63;
    Cd[jl * 68 + c] = cond[((long)(b * N_ + jh * 64 + jl) * N_ + i) * CI + c];
  }
  __syncthreads();
  gemm8x8(acc, Wt, Cd, jg, og);

  // ---- store ----
  long base = ((long)(b * N_ + i) * N_ + jh * 64) * CO;
  #pragma unroll
  for (int k = 0; k < 8; k++) {
    long rowb = base + (long)(jg + 8 * k) * CO;
    #pragma unroll
    for (int m = 0; m < 8; m++)
      Cp[rowb + og + 16 * m] = acc[k][m];
  }
}

// =====================================================================
// k_red: out[b,t,i,o] = silu( A[t,i,o] + max_j(Bp[t,j,o] + Cp[i,j,o]) )
// grid 256 = (b,i), 1024 threads = 16 waves/CU.
// thread = (t = tid>>6, jh = lane>>5, o-quad = lane&31); shfl_xor(32) combines j-halves.
// Fast path: max >= 0 -> silu(max) (monotone); exact slow path otherwise.
// =====================================================================
__device__ float slow_silu_max(const float* __restrict__ BpT,
                               const float* __restrict__ CpS, float a, int o) {
  float m = -3.4e38f;
  for (int j = 0; j < 128; j++) {
    float v = a + BpT[j * CO + o] + CpS[j * CO + o];
    float sil = v / (1.0f + __expf(-v));
    m = fmaxf(m, sil);
  }
  return m;
}
__device__ __forceinline__ float fast_silu(float s) {
  return s / (1.0f + __expf(-s));
}

__global__ __launch_bounds__(1024) void k_red(
    const float* __restrict__ A, const float* __restrict__ Bp,
    const float* __restrict__ Cp, float* __restrict__ out)
{
  __shared__ __align__(16) float CpL[128 * 128];  // 64 KB

  int blk = blockIdx.x;
  int i = blk & 127;
  int b = blk >> 7;
  int tid = threadIdx.x;

  // stage Cp[b,i,:,:] (4096 float4, coalesced)
  const float4* src = (const float4*)(Cp + ((long)(b * N_ + i)) * N_ * CO);
  float4* CpL4 = (float4*)CpL;
  #pragma unroll
  for (int k = 0; k < 4; k++) CpL4[tid + k * 1024] = src[tid + k * 1024];
  __syncthreads();

  int t    = tid >> 6;
  int lane = tid & 63;
  int jh   = lane >> 5;
  int o4   = lane & 31;

  const float* BpT = Bp + (long)(b * T_ + t) * N_ * CO;
  const float4* Bp4 = (const float4*)BpT;

  float4 m0 = make_float4(-3.4e38f, -3.4e38f, -3.4e38f, -3.4e38f);
  float4 m1 = m0;
  int j0 = jh * 64;
  #pragma unroll 2
  for (int jj = 0; jj < 64; jj += 2) {
    int ja = (j0 + jj) * 32 + o4;
    int jb = ja + 32;
    float4 ba = Bp4[ja], ca = CpL4[ja];
    float4 bb = Bp4[jb], cb = CpL4[jb];
    m0 = f4max(m0, f4add(ba, ca));
    m1 = f4max(m1, f4add(bb, cb));
  }
  float4 m = f4max(m0, m1);
  // combine the two j-halves across the wave (lane ^ 32)
  float4 mo;
  mo.x = __shfl_xor(m.x, 32, 64);
  mo.y = __shfl_xor(m.y, 32, 64);
  mo.z = __shfl_xor(m.z, 32, 64);
  mo.w = __shfl_xor(m.w, 32, 64);
  m = f4max(m, mo);

  long abase = ((long)(b * T_ + t) * N_ + i) * CO + o4 * 4;
  float4 av = *(const float4*)&A[abase];
  float4 s = f4add(m, av);
  if (jh == 0) {
    float4 r;
    r.x = (s.x >= 0.0f) ? fast_silu(s.x) : slow_silu_max(BpT, CpL, av.x, o4 * 4 + 0);
    r.y = (s.y >= 0.0f) ? fast_silu(s.y) : slow_silu_max(BpT, CpL, av.y, o4 * 4 + 1);
    r.z = (s.z >= 0.0f) ? fast_silu(s.z) : slow_silu_max(BpT, CpL, av.z, o4 * 4 + 2);
    r.w = (s.w >= 0.0f) ? fast_silu(s.w) : slow_silu_max(BpT, CpL, av.w, o4 * 4 + 3);
    *(float4*)&out[abase] = r;
  }
}

extern "C" void kernel_launch(void* const* d_in, const int* in_sizes, int n_in,
                              void* d_out, int out_size, void* d_ws, size_t ws_size,
                              hipStream_t stream) {
  const float* x    = (const float*)d_in[0];   // (2,16,128,64)
  const float* cond = (const float*)d_in[1];   // (2,128,128,64)
  const float* W    = (const float*)d_in[2];   // (512,128)
  const float* bias = (const float*)d_in[3];   // (128,)
  float* out = (float*)d_out;                  // (2,16,128,128)

  float* ws = (float*)d_ws;
  float* A  = ws + A_OFF;
  float* Bp = ws + BP_OFF;
  float* WT = ws + WT_OFF;
  float* Cp = ws + CP_OFF;

  k_prep<<<48, 256, 0, stream>>>(W, WT);
  k_ab<<<512, 128, 0, stream>>>(x, WT, bias, A, Bp);
  k_cp<<<512, 128, 0, stream>>>(cond, W, Cp);
  k_red<<<256, 1024, 0, stream>>>(A, Bp, Cp, out);
}